// Round 4
// baseline (1092.890 us; speedup 1.0000x reference)
//
#include <hip/hip_runtime.h>

#define BATCH 8
#define NPTS 4096
#define NSAMP 512   // npoint = NPTS/8

#define ROW_SHR(n) (0x110 | (n))
#define ROW_BCAST15 0x142
#define ROW_BCAST31 0x143

// f32 max-combine via DPP (1 mov_dpp + 1 v_max_f32). bound_ctrl/row_mask
// holes deliver 0.0f, which is the identity for distances >= 0.
template <int CTRL, int RMASK>
__device__ __forceinline__ float fmax_dpp(float x) {
  int t = __builtin_amdgcn_update_dpp(0, __float_as_int(x), CTRL, RMASK, 0xf, true);
  return fmaxf(x, __int_as_float(t));
}

// ---------------------------------------------------------------------------
// Kernel A: farthest point sampling. One block per batch, 256 threads.
// Thread t owns points [16t, 16t+16)  =>  lane order == index order, so
// ballot + ffs gives the exact first-occurrence argmax (np semantics).
// Exact fp32 (no FMA contraction) so selection matches numpy bit-for-bit.
// ---------------------------------------------------------------------------
__global__ __launch_bounds__(256) void fps_kernel(const float* __restrict__ pcd,
                                                  float* __restrict__ new_xyz) {
  __shared__ float4 slot[2][4];   // per-wave winner (x,y,z,val), parity dbuf

  const int b = blockIdx.x;
  const int t = threadIdx.x;
  const int wave = t >> 6;
  const int lane = t & 63;
  const float* xb = pcd + (size_t)b * NPTS * 3;

  float X[16], Y[16], Z[16], mind[16];
#pragma unroll
  for (int j = 0; j < 16; ++j) {
    int i = t * 16 + j;
    X[j] = xb[i * 3 + 0];
    Y[j] = xb[i * 3 + 1];
    Z[j] = xb[i * 3 + 2];
    mind[j] = 10000000000.0f;
  }

  float px = xb[0], py = xb[1], pz = xb[2];   // first sample is index 0

  for (int it = 0; it < NSAMP; ++it) {
    if (t == 0) {
      size_t o = ((size_t)b * NSAMP + it) * 3;
      new_xyz[o + 0] = px; new_xyz[o + 1] = py; new_xyz[o + 2] = pz;
    }
    // ---- update min-dist + local argmax, tracking winner coords ----------
    float bv = -1.0f, bx = 0.0f, by = 0.0f, bz = 0.0f;
#pragma unroll
    for (int j = 0; j < 16; ++j) {
      float dx = __fsub_rn(X[j], px);
      float dy = __fsub_rn(Y[j], py);
      float dz = __fsub_rn(Z[j], pz);
      float d = __fadd_rn(__fadd_rn(__fmul_rn(dx, dx), __fmul_rn(dy, dy)),
                          __fmul_rn(dz, dz));
      float m = fminf(mind[j], d);
      mind[j] = m;
      if (m > bv) { bv = m; bx = X[j]; by = Y[j]; bz = Z[j]; }  // first occ.
    }
    // ---- wave max via f32 DPP; exact tie -> lowest lane = lowest index ---
    float m = bv;
    m = fmax_dpp<ROW_SHR(1), 0xf>(m);
    m = fmax_dpp<ROW_SHR(2), 0xf>(m);
    m = fmax_dpp<ROW_SHR(4), 0xf>(m);
    m = fmax_dpp<ROW_SHR(8), 0xf>(m);
    m = fmax_dpp<ROW_BCAST15, 0xa>(m);
    m = fmax_dpp<ROW_BCAST31, 0xc>(m);
    float wmax = __int_as_float(
        __builtin_amdgcn_readlane(__float_as_int(m), 63));
    unsigned long long msk = __ballot(bv == wmax);
    int wl = __ffsll(msk) - 1;
    if (lane == wl) slot[it & 1][wave] = make_float4(bx, by, bz, wmax);
    __syncthreads();
    // ---- cross-wave combine (strict > keeps lowest wave = lowest index) --
    float4 s0 = slot[it & 1][0], s1 = slot[it & 1][1];
    float4 s2 = slot[it & 1][2], s3 = slot[it & 1][3];
    float4 cur = s0;
    if (s1.w > cur.w) cur = s1;
    if (s2.w > cur.w) cur = s2;
    if (s3.w > cur.w) cur = s3;
    px = cur.x; py = cur.y; pz = cur.z;
  }
}

// ---------------------------------------------------------------------------
// Weight prep: transpose each w[cin][cout] into wt[cout][cinp] (cin padded
// to a multiple of 4 with zeros) so MLP threads can float4-load weights.
// ---------------------------------------------------------------------------
__device__ __forceinline__ void tsec(int g, const float* __restrict__ w,
                                     float* __restrict__ wt, int cin, int cinp,
                                     int cout, int base) {
  int local = g - base;
  if (local < 0 || local >= cinp * cout) return;
  int oc = local / cinp, ic = local % cinp;
  wt[base + local] = (ic < cin) ? w[ic * cout + oc] : 0.0f;
}

#define W00 0
#define W01 128
#define W02 1152
#define W10 3200
#define W11 3456
#define W12 7552
#define W20 15744
#define W21 16000
#define W22 22144
#define WT_TOTAL 34432

__global__ __launch_bounds__(256) void prep_kernel(
    const float* w00, const float* w01, const float* w02,
    const float* w10, const float* w11, const float* w12,
    const float* w20, const float* w21, const float* w22,
    float* __restrict__ wt) {
  int g = blockIdx.x * 256 + threadIdx.x;
  tsec(g, w00, wt, 3, 4, 32, W00);
  tsec(g, w01, wt, 32, 32, 32, W01);
  tsec(g, w02, wt, 32, 32, 64, W02);
  tsec(g, w10, wt, 3, 4, 64, W10);
  tsec(g, w11, wt, 64, 64, 64, W11);
  tsec(g, w12, wt, 64, 64, 128, W12);
  tsec(g, w20, wt, 3, 4, 64, W20);
  tsec(g, w21, wt, 64, 64, 96, W21);
  tsec(g, w22, wt, 96, 96, 128, W22);
}

// ---------------------------------------------------------------------------
// Tiled MLP layer, transposed weights: block = 16 n-threads x 16 oc-threads.
// h channel-major in LDS with padded row stride NTP (kills write conflicts).
// Per 4 input channels: TOC float4 weight loads + 4*TN LDS reads + 4*TOC*TN
// FMAs. FINAL: fuse bias+relu+max-over-n via LDS int atomicMax (vals >= 0).
// ---------------------------------------------------------------------------
template <int CINP, int COUT, int NT, int NTP, bool FINAL>
__device__ __forceinline__ void layerT(const float* __restrict__ wt,
                                       const float* __restrict__ bias,
                                       const float* hin, float* hout, int tid) {
  constexpr int TN = NT / 16;
  constexpr int TOC = COUT / 16;
  const int tn = tid & 15, toc = tid >> 4;
  float acc[TOC][TN];
#pragma unroll
  for (int j = 0; j < TOC; ++j) {
    float bj = bias[toc * TOC + j];
#pragma unroll
    for (int i = 0; i < TN; ++i) acc[j][i] = bj;
  }
#pragma unroll 4
  for (int c4 = 0; c4 < CINP / 4; ++c4) {
    float4 wv[TOC];
#pragma unroll
    for (int j = 0; j < TOC; ++j)
      wv[j] = *(const float4*)&wt[(toc * TOC + j) * CINP + c4 * 4];
    float hv[4][TN];
#pragma unroll
    for (int k = 0; k < 4; ++k)
#pragma unroll
      for (int i = 0; i < TN; ++i)
        hv[k][i] = hin[(c4 * 4 + k) * NTP + tn * TN + i];
#pragma unroll
    for (int j = 0; j < TOC; ++j)
#pragma unroll
      for (int i = 0; i < TN; ++i) {
        acc[j][i] = fmaf(hv[0][i], wv[j].x, acc[j][i]);
        acc[j][i] = fmaf(hv[1][i], wv[j].y, acc[j][i]);
        acc[j][i] = fmaf(hv[2][i], wv[j].z, acc[j][i]);
        acc[j][i] = fmaf(hv[3][i], wv[j].w, acc[j][i]);
      }
  }
  if (FINAL) {
#pragma unroll
    for (int j = 0; j < TOC; ++j) {
      float mx = 0.0f;  // relu floor
#pragma unroll
      for (int i = 0; i < TN; ++i) mx = fmaxf(mx, acc[j][i]);
      atomicMax((int*)&hout[toc * TOC + j], __float_as_int(mx));
    }
  } else {
#pragma unroll
    for (int j = 0; j < TOC; ++j) {
      if (TN == 2) {
        float2 v = make_float2(fmaxf(acc[j][0], 0.0f),
                               TN > 1 ? fmaxf(acc[j][1], 0.0f) : 0.0f);
        *(float2*)&hout[(toc * TOC + j) * NTP + tn * TN] = v;
      } else {
#pragma unroll
        for (int i = 0; i < TN; ++i)
          hout[(toc * TOC + j) * NTP + tn * TN + i] = fmaxf(acc[j][i], 0.0f);
      }
    }
  }
}

// ---------------------------------------------------------------------------
// Kernel B: one block per (b, s) sample point.
// Phase 1: all 256 threads build per-chunk in-radius bitmasks for all 3
// radii (16 pipelined rounds). Phase 2: wave s walks scale-s masks to build
// its ordered index list. Phase 3: per-scale MLP + max (NT=32 tiles).
// ---------------------------------------------------------------------------
__global__ __launch_bounds__(256, 4) void msg_kernel(
    const float* __restrict__ pcd, const float* __restrict__ new_xyz,
    const float* __restrict__ wt,
    const float* __restrict__ b00, const float* __restrict__ b01,
    const float* __restrict__ b02, const float* __restrict__ b10,
    const float* __restrict__ b11, const float* __restrict__ b12,
    const float* __restrict__ b20, const float* __restrict__ b21,
    const float* __restrict__ b22,
    const float* __restrict__ wf, const float* __restrict__ bf,
    float* __restrict__ out) {
  __shared__ float hA[96 * 34];                  // 13056 B
  __shared__ float hB[64 * 34];                  //  8704 B
  __shared__ unsigned long long masks[3][64];    //  1536 B
  __shared__ int lists[176];                     // 16 + 32 + 128
  __shared__ float feat[320];

  const int bs = blockIdx.x;
  const int b = bs >> 9;
  const int tid = threadIdx.x;
  const int lane = tid & 63;
  const int wave = tid >> 6;
  const float* xb = pcd + (size_t)b * NPTS * 3;

  const float cx = new_xyz[(size_t)bs * 3 + 0];
  const float cy = new_xyz[(size_t)bs * 3 + 1];
  const float cz = new_xyz[(size_t)bs * 3 + 2];

  for (int c = tid; c < 320; c += 256) feat[c] = 0.0f;

  // ---- phase 1: all threads, 16 rounds, 3 ballots each -> 192 masks ----
  const float r2a = (float)(0.1 * 0.1);
  const float r2b = (float)(0.2 * 0.2);
  const float r2c = (float)(0.4 * 0.4);
#pragma unroll 4
  for (int j = 0; j < 16; ++j) {
    int i = (j << 8) | tid;
    const float* p = xb + i * 3;
    float dx = __fsub_rn(cx, p[0]);
    float dy = __fsub_rn(cy, p[1]);
    float dz = __fsub_rn(cz, p[2]);
    float sq = __fadd_rn(__fadd_rn(__fmul_rn(dx, dx), __fmul_rn(dy, dy)),
                         __fmul_rn(dz, dz));
    unsigned long long m0 = __ballot(sq < r2a);
    unsigned long long m1 = __ballot(sq < r2b);
    unsigned long long m2 = __ballot(sq < r2c);
    if (lane == 0) {
      int c = (j << 2) | wave;
      masks[0][c] = m0; masks[1][c] = m1; masks[2][c] = m2;
    }
  }
  __syncthreads();

  // ---- phase 2: wave s builds ordered list for scale s ----
  if (wave < 3) {
    const int ns  = (wave == 0) ? 16 : (wave == 1) ? 32 : 128;
    const int off = (wave == 0) ? 0  : (wave == 1) ? 16 : 48;
    int cnt = 0;
    for (int c = 0; c < 64; ++c) {
      unsigned long long m = masks[wave][c];
      if (m) {
        int bit = (int)((m >> lane) & 1ull);
        int pos = cnt + (int)__popcll(m & ((1ull << lane) - 1ull));
        if (bit && pos < ns) lists[off + pos] = (c << 6) | lane;
        cnt += (int)__popcll(m);
        if (cnt >= ns) break;
      }
    }
    if (cnt > ns) cnt = ns;
    int first = lists[off];              // center is always in-radius
    for (int k = cnt + lane; k < ns; k += 64) lists[off + k] = first;
  }
  __syncthreads();

  // ---- scale 0: ns=16, 3->32->32->64 -> feat[0:64) ----
  {
    if (tid < 16) {
      int j = lists[tid];
      const float* p = xb + j * 3;
      hA[0 * 18 + tid] = __fsub_rn(p[0], cx);
      hA[1 * 18 + tid] = __fsub_rn(p[1], cy);
      hA[2 * 18 + tid] = __fsub_rn(p[2], cz);
      hA[3 * 18 + tid] = 0.0f;
    }
    __syncthreads();
    layerT<4, 32, 16, 18, false>(wt + W00, b00, hA, hB, tid);  __syncthreads();
    layerT<32, 32, 16, 18, false>(wt + W01, b01, hB, hA, tid); __syncthreads();
    layerT<32, 64, 16, 18, true>(wt + W02, b02, hA, feat + 0, tid);
    __syncthreads();
  }
  // ---- scale 1: ns=32, 3->64->64->128 -> feat[64:192) ----
  {
    if (tid < 32) {
      int j = lists[16 + tid];
      const float* p = xb + j * 3;
      hA[0 * 34 + tid] = __fsub_rn(p[0], cx);
      hA[1 * 34 + tid] = __fsub_rn(p[1], cy);
      hA[2 * 34 + tid] = __fsub_rn(p[2], cz);
      hA[3 * 34 + tid] = 0.0f;
    }
    __syncthreads();
    layerT<4, 64, 32, 34, false>(wt + W10, b10, hA, hB, tid);  __syncthreads();
    layerT<64, 64, 32, 34, false>(wt + W11, b11, hB, hA, tid); __syncthreads();
    layerT<64, 128, 32, 34, true>(wt + W12, b12, hA, feat + 64, tid);
    __syncthreads();
  }
  // ---- scale 2: ns=128 in 4 tiles of 32, 3->64->96->128 -> feat[192:320) --
  for (int tile = 0; tile < 4; ++tile) {
    if (tid < 32) {
      int j = lists[48 + tile * 32 + tid];
      const float* p = xb + j * 3;
      hA[0 * 34 + tid] = __fsub_rn(p[0], cx);
      hA[1 * 34 + tid] = __fsub_rn(p[1], cy);
      hA[2 * 34 + tid] = __fsub_rn(p[2], cz);
      hA[3 * 34 + tid] = 0.0f;
    }
    __syncthreads();
    layerT<4, 64, 32, 34, false>(wt + W20, b20, hA, hB, tid);  __syncthreads();
    layerT<64, 96, 32, 34, false>(wt + W21, b21, hB, hA, tid); __syncthreads();
    layerT<96, 128, 32, 34, true>(wt + W22, b22, hA, feat + 192, tid);
    __syncthreads();
  }

  // ---- final linear 320 -> 1 ----
  if (tid < 64) {
    float s = 0.0f;
#pragma unroll
    for (int c = 0; c < 5; ++c) s += feat[tid + c * 64] * wf[tid + c * 64];
#pragma unroll
    for (int o = 32; o > 0; o >>= 1) s += __shfl_down(s, o);
    if (tid == 0) out[bs] = s + bf[0];
  }
}

extern "C" void kernel_launch(void* const* d_in, const int* in_sizes, int n_in,
                              void* d_out, int out_size, void* d_ws, size_t ws_size,
                              hipStream_t stream) {
  const float* pcd = (const float*)d_in[0];
  float* wsf = (float*)d_ws;
  float* new_xyz = wsf;                 // 8*512*3 = 12288 floats (48 KB)
  float* wt = wsf + 12288;              // 34432 floats (transposed weights)

  prep_kernel<<<(WT_TOTAL + 255) / 256, 256, 0, stream>>>(
      (const float*)d_in[1], (const float*)d_in[3], (const float*)d_in[5],
      (const float*)d_in[7], (const float*)d_in[9], (const float*)d_in[11],
      (const float*)d_in[13], (const float*)d_in[15], (const float*)d_in[17],
      wt);

  fps_kernel<<<BATCH, 256, 0, stream>>>(pcd, new_xyz);

  msg_kernel<<<BATCH * NSAMP, 256, 0, stream>>>(
      pcd, new_xyz, wt,
      (const float*)d_in[2],  (const float*)d_in[4],  (const float*)d_in[6],
      (const float*)d_in[8],  (const float*)d_in[10], (const float*)d_in[12],
      (const float*)d_in[14], (const float*)d_in[16], (const float*)d_in[18],
      (const float*)d_in[19], (const float*)d_in[20],
      (float*)d_out);
}